// Round 7
// baseline (243.381 us; speedup 1.0000x reference)
//
#include <hip/hip_runtime.h>
#include <hip/hip_bf16.h>

// StyleGAN2 modulated conv, fp32 in/out, bf16 MFMA implicit GEMM (NHWC).
// b=16, c_in=256, c_out=256, h=w=64, k=3.
#define BATCH 16
#define CIN   256
#define COUT  256
#define HH    64
#define WW    64
#define SDIM  512
#define NPIX  4096
#define PADH  66
#define PADW  66

typedef __hip_bfloat16 bf16;
typedef __attribute__((ext_vector_type(8))) short short8;   // 8 bf16
typedef __attribute__((ext_vector_type(4))) float f32x4;

__device__ __forceinline__ void glds16(const void* g, void* l) {
    __builtin_amdgcn_global_load_lds(
        (const __attribute__((address_space(1))) unsigned int*)g,
        (__attribute__((address_space(3))) unsigned int*)l, 16, 0, 0);
}

#define BAR()   __builtin_amdgcn_s_barrier()
#define VM0()   asm volatile("s_waitcnt vmcnt(0)" ::: "memory")

// ---------------------------------------------------------------------------
// P1: s[b][ci] = dot(w_style[b,:], aff_w[ci,:]) + aff_b[ci] + 1
// ---------------------------------------------------------------------------
__global__ __launch_bounds__(256) void style_kernel(
    const float* __restrict__ w_style, const float* __restrict__ aff_w,
    const float* __restrict__ aff_b, float* __restrict__ s)
{
    const int b = blockIdx.x, c = threadIdx.x;
    __shared__ float ws[SDIM];
    for (int j = c; j < SDIM; j += 256) ws[j] = w_style[b * SDIM + j];
    __syncthreads();
    const float* aw = aff_w + (size_t)c * SDIM;
    float acc = 0.f;
#pragma unroll 4
    for (int j = 0; j < SDIM; j += 4) {
        const float4 a = *(const float4*)(aw + j);
        acc += a.x * ws[j] + a.y * ws[j + 1] + a.z * ws[j + 2] + a.w * ws[j + 3];
    }
    s[b * CIN + c] = acc + aff_b[c] + 1.0f;
}

// ---------------------------------------------------------------------------
// P2 fused: blocks [0,4096) = weight mod/demod -> wt[b][r][co][ci] bf16
//           blocks [4096,5152) = x NCHW fp32 -> xt[b][66][66][ci] bf16 (zero halo)
// ---------------------------------------------------------------------------
__global__ __launch_bounds__(256) void prep_kernel(
    const float* __restrict__ W, const float* __restrict__ s,
    const float* __restrict__ x,
    bf16* __restrict__ wt, bf16* __restrict__ xt)
{
    __shared__ union {
        float wl[CIN * 9];          // 9.2 KB (wgt part)
        bf16  t[WW][CIN + 2];       // 33 KB  (xpose part)
        float red4[4];
    } sh;
    const int tid = threadIdx.x;

    if (blockIdx.x < BATCH * COUT) {
        // ---- weight branch: one block per (b,co) ----
        const int bc = blockIdx.x, b = bc >> 8, co = bc & 255, ci = tid;
        const float* wrow = W + (size_t)co * (CIN * 9);
        for (int i = ci; i < CIN * 9 / 4; i += 256)
            *(float4*)&sh.wl[i * 4] = *(const float4*)(wrow + i * 4);
        __syncthreads();
        const float sv = s[b * CIN + ci];
        float m[9], part = 0.f;
#pragma unroll
        for (int r = 0; r < 9; ++r) { m[r] = sh.wl[ci * 9 + r] * sv; part += m[r] * m[r]; }
#pragma unroll
        for (int off = 32; off > 0; off >>= 1)
            part += __shfl_down(part, off, 64);
        __syncthreads();                    // protect union before re-use
        __shared__ float red[4];
        if ((ci & 63) == 0) red[ci >> 6] = part;
        __syncthreads();
        const float d = rsqrtf(red[0] + red[1] + red[2] + red[3] + 1e-8f);
#pragma unroll
        for (int r = 0; r < 9; ++r)
            wt[(((size_t)b * 9 + r) * COUT + co) * CIN + ci] = __float2bfloat16(m[r] * d);
    } else {
        // ---- transpose branch: one block per padded row ----
        const int xb  = blockIdx.x - BATCH * COUT;
        const int row = xb % PADH, b = xb / PADH;
        bf16* orow = xt + (((size_t)b * PADH + row) * PADW) * CIN;

        if (row == 0 || row == PADH - 1) {
            const uint4 z = {0, 0, 0, 0};
            for (int i = tid; i < PADW * CIN / 8; i += 256) ((uint4*)orow)[i] = z;
            return;
        }
        const float* xr = x + ((size_t)b * CIN * NPIX) + (size_t)(row - 1) * WW;
        // phase 1: float4 coalesced reads, transpose into LDS (stride 258 -> 2-way)
        for (int i = tid; i < CIN * (WW / 4); i += 256) {
            const int ci = i >> 4, c4 = (i & 15) * 4;
            const float4 v = *(const float4*)(xr + (size_t)ci * NPIX + c4);
            sh.t[c4 + 0][ci] = __float2bfloat16(v.x);
            sh.t[c4 + 1][ci] = __float2bfloat16(v.y);
            sh.t[c4 + 2][ci] = __float2bfloat16(v.z);
            sh.t[c4 + 3][ci] = __float2bfloat16(v.w);
        }
        __syncthreads();
        // phase 2: 8 bf16 per thread, uint4 global stores
        for (int i = tid; i < PADW * (CIN / 8); i += 256) {
            const int col = i >> 5, c8 = (i & 31) * 8;
            uint4 v = {0, 0, 0, 0};
            if (col > 0 && col < PADW - 1) {
                const unsigned* tp = (const unsigned*)&sh.t[col - 1][c8]; // 4B-aligned
                v.x = tp[0]; v.y = tp[1]; v.z = tp[2]; v.w = tp[3];
            }
            ((uint4*)orow)[i] = v;
        }
    }
}

// ---------------------------------------------------------------------------
// GEMM: out[b][co][px] = sum_{r,ci} wt[b][r][co][ci] * xt[b][y+dy+1][x+dx+1][ci]
// Round-7 = round-6 (proven 86.8us) with ONE structural change: 4 phases ->
// 2 phases per r-step (32-MFMA clusters). Mechanism: per-phase MFMA window
// doubles (620 -> 1240 cyc/SIMD), now covering the 12-read/wave return of the
// next phase's fragments; barriers/step 8 -> 4; phase-entry lgkm stalls 4 -> 2.
//   block = 256co x 256px (4 pixel-rows), 8 waves, wave = 128co x 64px
//   Ash dbuf 2x32KB, Bsh 6x66x64 (reused across all 9 taps)
//   Phase A: read kk1 frags (12) + issue stageA(next); BAR; 32 MFMA kk0; BAR.
//   Phase B: [B restage at c-boundary]; VM0; BAR; read next-step kk0 frags
//            from Ash[nxt]; 32 MFMA kk1; BAR.
//   Visibility invariant: vmcnt(0) -> s_barrier -> read.
//   T1 (kept; FETCH 99->27MB proven): b = bid&15 -> same-b blocks on one XCD.
// XOR swizzle identical to proven round-0 (16B chunk ^ (row&7), 128B rows).
// ---------------------------------------------------------------------------
__global__ __launch_bounds__(512, 2) void gemm_kernel(
    const bf16* __restrict__ xt,   // [B][66][66][256]
    const bf16* __restrict__ wt,   // [B][9][256][256]
    float* __restrict__ out)       // [B][256][4096]
{
    const int bid = blockIdx.x;
    const int b  = bid & 15;            // T1: same-b blocks share an XCD
    const int nt = bid >> 4;            // 4-row pixel group: rows nt*4 .. nt*4+3
    const int tid  = threadIdx.x;
    const int wave = tid >> 6, lane = tid & 63;
    const int wm = wave >> 2, wn = wave & 3;   // 2 x 4 wave grid
    const int lm = lane & 15, quad = lane >> 4;

    __shared__ bf16 Ash[2][256 * 64];   // 2 x 32 KB, [co][ci] swizzled
    __shared__ bf16 Bsh[6 * PADW * 64]; // 50.7 KB, [row*66+col][ci] swizzled

    f32x4 acc[8][4] = {};

    const bf16* xb = xt + (size_t)b * PADH * PADW * CIN;
    const bf16* wb = wt + (size_t)b * 9 * COUT * CIN;

    int p0[4];
#pragma unroll
    for (int ni = 0; ni < 4; ++ni)
        p0[ni] = (1 + wn) * PADW + ni * 16 + lm + 1;

    // ---- staging helpers (glds16: linear LDS dest, inverse-swizzled source) ----
    auto stageA = [&](int r, int c, int buf) {
        const bf16* wr = wb + (size_t)r * (COUT * CIN) + c * 64;
#pragma unroll
        for (int k = 0; k < 4; ++k) {
            const int i = tid + k * 512;
            const int co = i >> 3, pc = i & 7;
            const int lc = pc ^ (co & 7);
            glds16(wr + co * CIN + lc * 8, Ash[buf] + i * 8);
        }
    };
    auto stageB = [&](int c) {
        const int ci0 = c * 64;
        for (int i = tid; i < 6 * PADW * 8; i += 512) {
            const int row = i / (PADW * 8);
            const int j   = i - row * (PADW * 8);
            const int col = j >> 3, pc = j & 7;
            const int p   = row * PADW + col;
            const int lc  = pc ^ (p & 7);
            glds16(xb + (((size_t)(nt * 4 + row) * PADW + col) * CIN + ci0 + lc * 8),
                   Bsh + i * 8);
        }
    };
    auto readA8 = [&](short8* af, int kk, int buf) {   // all 8 A frags of one kk
#pragma unroll
        for (int mi = 0; mi < 8; ++mi) {
            const int arow = wm * 128 + mi * 16 + lm;
            const int lc   = kk * 4 + quad;
            af[mi] = *(const short8*)(Ash[buf] + arow * 64 + (lc ^ (arow & 7)) * 8);
        }
    };
    auto readB4 = [&](short8* bfr, int kk, int dpx) {
#pragma unroll
        for (int ni = 0; ni < 4; ++ni) {
            const int p  = p0[ni] + dpx;
            const int lc = kk * 4 + quad;
            bfr[ni] = *(const short8*)(Bsh + p * 64 + (lc ^ (p & 7)) * 8);
        }
    };
    auto mfma32 = [&](const short8* af, const short8* bfr) {
        __builtin_amdgcn_s_setprio(1);
#pragma unroll
        for (int mi = 0; mi < 8; ++mi)
#pragma unroll
            for (int ni = 0; ni < 4; ++ni)
                acc[mi][ni] = __builtin_amdgcn_mfma_f32_16x16x32_bf16(
                    af[mi], bfr[ni], acc[mi][ni], 0, 0, 0);
        __builtin_amdgcn_s_setprio(0);
    };

    // ---- prologue: B(c=0) + A(r=0,c=0) -> Ash[0]; full drain; pre-read kk0 ----
    stageB(0);
    stageA(0, 0, 0);
    __syncthreads();

    short8 a0[8], b0[4], a1[8], b1[4];
    readA8(a0, 0, 0);
    readB4(b0, 0, -PADW - 1);          // r=0: dy=-1, dx=-1

    int cur = 0;
#pragma unroll 1
    for (int c = 0; c < 4; ++c) {
#pragma unroll 1
        for (int r = 0; r < 9; ++r) {
            const bool last = (c == 3) && (r == 8);
            const int nr = (r == 8) ? 0 : r + 1;
            const int dpx  = (r / 3 - 1) * PADW + (r % 3 - 1);
            const int dpxn = (nr / 3 - 1) * PADW + (nr % 3 - 1);

            // ---- Phase A: read kk1 frags; issue A(next); 32 MFMA on kk0 ----
            readA8(a1, 1, cur);
            readB4(b1, 1, dpx);
            if (!last) stageA(nr, (r == 8) ? c + 1 : c, cur ^ 1);
            BAR();
            mfma32(a0, b0);             // kk0, all 8x4 frags
            BAR();

            // ---- Phase B: [B restage]; drain; read next kk0; 32 MFMA on kk1 ----
            if (r == 8 && c < 3) {
                __syncthreads();        // full lgkm+vm drain; old Bsh reads retired
                stageB(c + 1);
            }
            if (!last) VM0();
            BAR();
            if (!last) {
                readA8(a0, 0, cur ^ 1);
                readB4(b0, 0, dpxn);
            }
            mfma32(a1, b1);             // kk1, all 8x4 frags
            BAR();
            cur ^= 1;
        }
    }

    // epilogue: C/D layout col=lane&15 (px), row=quad*4+v (co)
    float* ob = out + (size_t)b * COUT * NPIX + nt * 256;
#pragma unroll
    for (int mi = 0; mi < 8; ++mi) {
        const int cl = wm * 128 + mi * 16 + quad * 4;
#pragma unroll
        for (int ni = 0; ni < 4; ++ni) {
            const int px = wn * 64 + ni * 16 + lm;
#pragma unroll
            for (int v = 0; v < 4; ++v)
                ob[(size_t)(cl + v) * NPIX + px] = acc[mi][ni][v];
        }
    }
}

// ---------------------------------------------------------------------------
// Fallback (round-2, known correct) for small workspace.
// ---------------------------------------------------------------------------
template <bool FUSE_S>
__global__ __launch_bounds__(256) void conv_mod_kernel(
    const float* __restrict__ x, const float* __restrict__ W,
    const float* __restrict__ s_pre, const float* __restrict__ w_style,
    const float* __restrict__ aff_w, const float* __restrict__ aff_b,
    float* __restrict__ out)
{
    const int bc = blockIdx.x, b = bc >> 8, co = bc & 255, tid = threadIdx.x;
    __shared__ float wsh[CIN * 9];
    __shared__ float red[CIN];
    float sv;
    if (FUSE_S) {
        __shared__ float wst[SDIM];
        for (int j = tid; j < SDIM; j += 256) wst[j] = w_style[b * SDIM + j];
        __syncthreads();
        const float* aw = aff_w + tid * SDIM;
        float a2 = 0.f;
#pragma unroll 8
        for (int j = 0; j < SDIM; ++j) a2 += wst[j] * aw[j];
        sv = a2 + aff_b[tid] + 1.0f;
    } else sv = s_pre[b * CIN + tid];
    {
        const float* wp = W + (co * CIN + tid) * 9;
        float m[9], part = 0.f;
#pragma unroll
        for (int r = 0; r < 9; ++r) { m[r] = wp[r] * sv; part += m[r] * m[r]; }
        red[tid] = part;
        __syncthreads();
#pragma unroll
        for (int off = CIN / 2; off > 0; off >>= 1) {
            if (tid < off) red[tid] += red[tid + off];
            __syncthreads();
        }
        const float d = rsqrtf(red[0] + 1e-8f);
#pragma unroll
        for (int r = 0; r < 9; ++r) wsh[tid * 9 + r] = m[r] * d;
        __syncthreads();
    }
    const int p = blockIdx.y * 256 + tid, y = p >> 6, xx = p & 63;
    const bool vt = y > 0, vb = y < HH - 1, vl = xx > 0, vr = xx < WW - 1;
    const bool val[9] = { vt && vl, vt, vt && vr, vl, true, vr, vb && vl, vb, vb && vr };
    const int off9[9] = { -WW - 1, -WW, -WW + 1, -1, 0, 1, WW - 1, WW, WW + 1 };
    const float* xbp = x + (size_t)b * CIN * NPIX + p;
    float acc = 0.f;
    for (int ci = 0; ci < CIN; ++ci) {
        const float* xp = xbp + ci * NPIX;
        const float* wp = wsh + ci * 9;
#pragma unroll
        for (int r = 0; r < 9; ++r) acc += (val[r] ? xp[off9[r]] : 0.f) * wp[r];
    }
    out[(size_t)bc * NPIX + p] = acc;
}

// ---------------------------------------------------------------------------
extern "C" void kernel_launch(void* const* d_in, const int* in_sizes, int n_in,
                              void* d_out, int out_size, void* d_ws, size_t ws_size,
                              hipStream_t stream) {
    const float* x       = (const float*)d_in[0];
    const float* w_style = (const float*)d_in[1];
    const float* W       = (const float*)d_in[2];
    const float* aff_w   = (const float*)d_in[3];
    const float* aff_b   = (const float*)d_in[4];
    float* out = (float*)d_out;

    const size_t wt_off  = 65536;
    const size_t wt_sz   = (size_t)BATCH * 9 * COUT * CIN * sizeof(bf16);
    const size_t xt_off  = wt_off + wt_sz;
    const size_t xt_sz   = (size_t)BATCH * PADH * PADW * CIN * sizeof(bf16);
    const size_t need    = xt_off + xt_sz;

    if (ws_size >= need) {
        float* s  = (float*)d_ws;
        bf16* wt  = (bf16*)((char*)d_ws + wt_off);
        bf16* xt  = (bf16*)((char*)d_ws + xt_off);
        style_kernel<<<dim3(BATCH), dim3(256), 0, stream>>>(w_style, aff_w, aff_b, s);
        prep_kernel<<<dim3(BATCH * COUT + BATCH * PADH), dim3(256), 0, stream>>>(
            W, s, x, wt, xt);
        gemm_kernel<<<dim3(BATCH * 16), dim3(512), 0, stream>>>(xt, wt, out);
    } else if (ws_size >= (size_t)(BATCH * CIN * sizeof(float))) {
        float* s = (float*)d_ws;
        style_kernel<<<dim3(BATCH), dim3(256), 0, stream>>>(w_style, aff_w, aff_b, s);
        conv_mod_kernel<false><<<dim3(BATCH * COUT, NPIX / 256), dim3(256), 0, stream>>>(
            x, W, s, w_style, aff_w, aff_b, out);
    } else {
        conv_mod_kernel<true><<<dim3(BATCH * COUT, NPIX / 256), dim3(256), 0, stream>>>(
            x, W, nullptr, w_style, aff_w, aff_b, out);
    }
}

// Round 8
// 214.993 us; speedup vs baseline: 1.1320x; 1.1320x over previous
//
#include <hip/hip_runtime.h>
#include <hip/hip_bf16.h>

// StyleGAN2 modulated conv, fp32 in/out, bf16 MFMA implicit GEMM (NHWC).
// b=16, c_in=256, c_out=256, h=w=64, k=3.
#define BATCH 16
#define CIN   256
#define COUT  256
#define HH    64
#define WW    64
#define SDIM  512
#define NPIX  4096
#define PADH  66
#define PADW  66

typedef __hip_bfloat16 bf16;
typedef __attribute__((ext_vector_type(8))) short short8;   // 8 bf16
typedef __attribute__((ext_vector_type(4))) float f32x4;

__device__ __forceinline__ void glds16(const void* g, void* l) {
    __builtin_amdgcn_global_load_lds(
        (const __attribute__((address_space(1))) unsigned int*)g,
        (__attribute__((address_space(3))) unsigned int*)l, 16, 0, 0);
}

__device__ __forceinline__ unsigned pkbf2(float a, float b) {
    // low 16 bits = bf16(a), high = bf16(b)
    __hip_bfloat162 h;
    h.x = __float2bfloat16(a);
    h.y = __float2bfloat16(b);
    unsigned u;
    __builtin_memcpy(&u, &h, 4);
    return u;
}

#define BAR()   __builtin_amdgcn_s_barrier()
#define VM0()   asm volatile("s_waitcnt vmcnt(0)" ::: "memory")

// ---------------------------------------------------------------------------
// P1: s[b][ci] = dot(w_style[b,:], aff_w[ci,:]) + aff_b[ci] + 1
// ---------------------------------------------------------------------------
__global__ __launch_bounds__(256) void style_kernel(
    const float* __restrict__ w_style, const float* __restrict__ aff_w,
    const float* __restrict__ aff_b, float* __restrict__ s)
{
    const int b = blockIdx.x, c = threadIdx.x;
    __shared__ float ws[SDIM];
    for (int j = c; j < SDIM; j += 256) ws[j] = w_style[b * SDIM + j];
    __syncthreads();
    const float* aw = aff_w + (size_t)c * SDIM;
    float acc = 0.f;
#pragma unroll 4
    for (int j = 0; j < SDIM; j += 4) {
        const float4 a = *(const float4*)(aw + j);
        acc += a.x * ws[j] + a.y * ws[j + 1] + a.z * ws[j + 2] + a.w * ws[j + 3];
    }
    s[b * CIN + c] = acc + aff_b[c] + 1.0f;
}

// ---------------------------------------------------------------------------
// P2 fused: blocks [0,4096) = weight mod/demod -> wt[b][r][co][ci] bf16
//           blocks [4096,5152) = x NCHW fp32 -> xt[b][66][66][ci] bf16 (zero halo)
// Round-8: transpose phase-1 processes TWO adjacent ci per thread and packs
// bf16x2 -> one ds_write_b32 (64 scalar b16 LDS writes/thread -> 32 b32), with
// 2x float4 global reads per iteration. Weight branch: removed the redundant
// first __syncthreads (red[] is a separate allocation, not the union).
// ---------------------------------------------------------------------------
__global__ __launch_bounds__(256) void prep_kernel(
    const float* __restrict__ W, const float* __restrict__ s,
    const float* __restrict__ x,
    bf16* __restrict__ wt, bf16* __restrict__ xt)
{
    __shared__ union {
        float    wl[CIN * 9];               // 9.2 KB (wgt part)
        bf16     t[WW][CIN + 2];            // 33 KB  (xpose part; stride 258)
        unsigned t32[WW][(CIN + 2) / 2];    // same memory, uint view (516B rows)
    } sh;
    const int tid = threadIdx.x;

    if (blockIdx.x < BATCH * COUT) {
        // ---- weight branch: one block per (b,co) ----
        const int bc = blockIdx.x, b = bc >> 8, co = bc & 255, ci = tid;
        const float* wrow = W + (size_t)co * (CIN * 9);
        for (int i = ci; i < CIN * 9 / 4; i += 256)
            *(float4*)&sh.wl[i * 4] = *(const float4*)(wrow + i * 4);
        __syncthreads();
        const float sv = s[b * CIN + ci];
        float m[9], part = 0.f;
#pragma unroll
        for (int r = 0; r < 9; ++r) { m[r] = sh.wl[ci * 9 + r] * sv; part += m[r] * m[r]; }
#pragma unroll
        for (int off = 32; off > 0; off >>= 1)
            part += __shfl_down(part, off, 64);
        __shared__ float red[4];            // separate allocation (not the union)
        if ((ci & 63) == 0) red[ci >> 6] = part;
        __syncthreads();
        const float d = rsqrtf(red[0] + red[1] + red[2] + red[3] + 1e-8f);
#pragma unroll
        for (int r = 0; r < 9; ++r)
            wt[(((size_t)b * 9 + r) * COUT + co) * CIN + ci] = __float2bfloat16(m[r] * d);
    } else {
        // ---- transpose branch: one block per padded row ----
        const int xb  = blockIdx.x - BATCH * COUT;
        const int row = xb % PADH, b = xb / PADH;
        bf16* orow = xt + (((size_t)b * PADH + row) * PADW) * CIN;

        if (row == 0 || row == PADH - 1) {
            const uint4 z = {0, 0, 0, 0};
            for (int i = tid; i < PADW * CIN / 8; i += 256) ((uint4*)orow)[i] = z;
            return;
        }
        const float* xr = x + ((size_t)b * CIN * NPIX) + (size_t)(row - 1) * WW;
        // phase 1: 2x float4 coalesced reads (ci pair), transpose into LDS as
        // packed bf16x2 ds_write_b32 (ci even -> 4B aligned; 516B row stride)
        for (int i = tid; i < (CIN / 2) * (WW / 4); i += 256) {
            const int ci = (i >> 4) * 2, c4 = (i & 15) * 4;
            const float4 v0 = *(const float4*)(xr + (size_t)ci * NPIX + c4);
            const float4 v1 = *(const float4*)(xr + (size_t)(ci + 1) * NPIX + c4);
            sh.t32[c4 + 0][ci >> 1] = pkbf2(v0.x, v1.x);
            sh.t32[c4 + 1][ci >> 1] = pkbf2(v0.y, v1.y);
            sh.t32[c4 + 2][ci >> 1] = pkbf2(v0.z, v1.z);
            sh.t32[c4 + 3][ci >> 1] = pkbf2(v0.w, v1.w);
        }
        __syncthreads();
        // phase 2: 8 bf16 per thread, uint4 global stores
        for (int i = tid; i < PADW * (CIN / 8); i += 256) {
            const int col = i >> 5, c8 = (i & 31) * 8;
            uint4 v = {0, 0, 0, 0};
            if (col > 0 && col < PADW - 1) {
                const unsigned* tp = (const unsigned*)&sh.t[col - 1][c8]; // 4B-aligned
                v.x = tp[0]; v.y = tp[1]; v.z = tp[2]; v.w = tp[3];
            }
            ((uint4*)orow)[i] = v;
        }
    }
}

// ---------------------------------------------------------------------------
// GEMM: out[b][co][px] = sum_{r,ci} wt[b][r][co][ci] * xt[b][y+dy+1][x+dx+1][ci]
// EXACT round-6 kernel (proven 86.8us, VGPR 116, no spill): 4-phase r-step,
// Ash dbuf 2x32KB, Bsh 6x66x64, vmcnt(0)->s_barrier->read invariant, T1
// bid-decode (b = bid&15: same-b blocks share an XCD; FETCH 99->27MB proven).
// Schedule-variant record: 4-phase=85.4/86.8 (best), 2-phase=107 (VGPR cap),
// 3buf-counted=spill. Do not re-derive; this is the local optimum.
// ---------------------------------------------------------------------------
__global__ __launch_bounds__(512, 2) void gemm_kernel(
    const bf16* __restrict__ xt,   // [B][66][66][256]
    const bf16* __restrict__ wt,   // [B][9][256][256]
    float* __restrict__ out)       // [B][256][4096]
{
    const int bid = blockIdx.x;
    const int b  = bid & 15;            // T1: same-b blocks share an XCD
    const int nt = bid >> 4;            // 4-row pixel group: rows nt*4 .. nt*4+3
    const int tid  = threadIdx.x;
    const int wave = tid >> 6, lane = tid & 63;
    const int wm = wave >> 2, wn = wave & 3;   // 2 x 4 wave grid
    const int lm = lane & 15, quad = lane >> 4;

    __shared__ bf16 Ash[2][256 * 64];   // 2 x 32 KB, [co][ci] swizzled
    __shared__ bf16 Bsh[6 * PADW * 64]; // 50.7 KB, [row*66+col][ci] swizzled

    f32x4 acc[8][4] = {};

    const bf16* xb = xt + (size_t)b * PADH * PADW * CIN;
    const bf16* wb = wt + (size_t)b * 9 * COUT * CIN;

    int p0[4];
#pragma unroll
    for (int ni = 0; ni < 4; ++ni)
        p0[ni] = (1 + wn) * PADW + ni * 16 + lm + 1;

    // ---- staging helpers (glds16: linear LDS dest, inverse-swizzled source) ----
    auto stageA = [&](int r, int c, int buf) {
        const bf16* wr = wb + (size_t)r * (COUT * CIN) + c * 64;
#pragma unroll
        for (int k = 0; k < 4; ++k) {
            const int i = tid + k * 512;
            const int co = i >> 3, pc = i & 7;
            const int lc = pc ^ (co & 7);
            glds16(wr + co * CIN + lc * 8, Ash[buf] + i * 8);
        }
    };
    auto stageB = [&](int c) {
        const int ci0 = c * 64;
        for (int i = tid; i < 6 * PADW * 8; i += 512) {
            const int row = i / (PADW * 8);
            const int j   = i - row * (PADW * 8);
            const int col = j >> 3, pc = j & 7;
            const int p   = row * PADW + col;
            const int lc  = pc ^ (p & 7);
            glds16(xb + (((size_t)(nt * 4 + row) * PADW + col) * CIN + ci0 + lc * 8),
                   Bsh + i * 8);
        }
    };
    auto readA = [&](short8* af, int kk, int mih, int buf) {
#pragma unroll
        for (int mi = 0; mi < 4; ++mi) {
            const int arow = wm * 128 + (mih * 4 + mi) * 16 + lm;
            const int lc   = kk * 4 + quad;
            af[mi] = *(const short8*)(Ash[buf] + arow * 64 + (lc ^ (arow & 7)) * 8);
        }
    };
    auto readB = [&](short8* bfr, int kk, int dpx) {
#pragma unroll
        for (int ni = 0; ni < 4; ++ni) {
            const int p  = p0[ni] + dpx;
            const int lc = kk * 4 + quad;
            bfr[ni] = *(const short8*)(Bsh + p * 64 + (lc ^ (p & 7)) * 8);
        }
    };
    auto mfma16 = [&](int half, const short8* af, const short8* bfr) {
        __builtin_amdgcn_s_setprio(1);
#pragma unroll
        for (int mi = 0; mi < 4; ++mi)
#pragma unroll
            for (int ni = 0; ni < 4; ++ni)
                acc[half * 4 + mi][ni] = __builtin_amdgcn_mfma_f32_16x16x32_bf16(
                    af[mi], bfr[ni], acc[half * 4 + mi][ni], 0, 0, 0);
        __builtin_amdgcn_s_setprio(0);
    };

    // ---- prologue: B(c=0) + A(r=0,c=0) -> Ash[0]; full drain; pre-read F0 ----
    stageB(0);
    stageA(0, 0, 0);
    __syncthreads();

    short8 afE[4], afO[4], bfE[4], bfO[4];
    readA(afE, 0, 0, 0);
    readB(bfE, 0, -PADW - 1);          // r=0: dy=-1, dx=-1

    int cur = 0;
#pragma unroll 1
    for (int c = 0; c < 4; ++c) {
#pragma unroll 1
        for (int r = 0; r < 9; ++r) {
            const bool last = (c == 3) && (r == 8);
            const int nr = (r == 8) ? 0 : r + 1;
            const int dpx  = (r / 3 - 1) * PADW + (r % 3 - 1);
            const int dpxn = (nr / 3 - 1) * PADW + (nr % 3 - 1);

            // phase 0: read F1 (afO: kk0, mi4-7); issue A(next) into Ash[cur^1]
            readA(afO, 0, 1, cur);
            if (!last) stageA(nr, (r == 8) ? c + 1 : c, cur ^ 1);
            BAR();
            mfma16(0, afE, bfE);        // kk0, acc half 0
            BAR();

            // phase 1: read F2 (afE: kk1 mi0-3; bfO: kk1)
            readA(afE, 1, 0, cur);
            readB(bfO, 1, dpx);
            BAR();
            mfma16(1, afO, bfE);        // kk0, acc half 1
            BAR();

            // phase 2: [B restage at tap boundary]; read F3 (afO: kk1 mi4-7)
            if (r == 8 && c < 3) {
                __syncthreads();        // all waves' old-B ds_reads retired + drain
                stageB(c + 1);
            }
            readA(afO, 1, 1, cur);
            BAR();
            mfma16(0, afE, bfO);        // kk1, acc half 0  (same acc as phase 0)
            BAR();

            // phase 3: drain staged A(next)[+B(next)] -> barrier -> THEN read F0'
            if (!last) VM0();
            BAR();
            if (!last) {
                readA(afE, 0, 0, cur ^ 1);
                readB(bfE, 0, dpxn);
            }
            mfma16(1, afO, bfO);        // kk1, acc half 1  (same acc as phase 1)
            BAR();
            cur ^= 1;
        }
    }

    // epilogue: C/D layout col=lane&15 (px), row=quad*4+v (co)
    float* ob = out + (size_t)b * COUT * NPIX + nt * 256;
#pragma unroll
    for (int mi = 0; mi < 8; ++mi) {
        const int cl = wm * 128 + mi * 16 + quad * 4;
#pragma unroll
        for (int ni = 0; ni < 4; ++ni) {
            const int px = wn * 64 + ni * 16 + lm;
#pragma unroll
            for (int v = 0; v < 4; ++v)
                ob[(size_t)(cl + v) * NPIX + px] = acc[mi][ni][v];
        }
    }
}

// ---------------------------------------------------------------------------
// Fallback (round-2, known correct) for small workspace.
// ---------------------------------------------------------------------------
template <bool FUSE_S>
__global__ __launch_bounds__(256) void conv_mod_kernel(
    const float* __restrict__ x, const float* __restrict__ W,
    const float* __restrict__ s_pre, const float* __restrict__ w_style,
    const float* __restrict__ aff_w, const float* __restrict__ aff_b,
    float* __restrict__ out)
{
    const int bc = blockIdx.x, b = bc >> 8, co = bc & 255, tid = threadIdx.x;
    __shared__ float wsh[CIN * 9];
    __shared__ float red[CIN];
    float sv;
    if (FUSE_S) {
        __shared__ float wst[SDIM];
        for (int j = tid; j < SDIM; j += 256) wst[j] = w_style[b * SDIM + j];
        __syncthreads();
        const float* aw = aff_w + tid * SDIM;
        float a2 = 0.f;
#pragma unroll 8
        for (int j = 0; j < SDIM; ++j) a2 += wst[j] * aw[j];
        sv = a2 + aff_b[tid] + 1.0f;
    } else sv = s_pre[b * CIN + tid];
    {
        const float* wp = W + (co * CIN + tid) * 9;
        float m[9], part = 0.f;
#pragma unroll
        for (int r = 0; r < 9; ++r) { m[r] = wp[r] * sv; part += m[r] * m[r]; }
        red[tid] = part;
        __syncthreads();
#pragma unroll
        for (int off = CIN / 2; off > 0; off >>= 1) {
            if (tid < off) red[tid] += red[tid + off];
            __syncthreads();
        }
        const float d = rsqrtf(red[0] + 1e-8f);
#pragma unroll
        for (int r = 0; r < 9; ++r) wsh[tid * 9 + r] = m[r] * d;
        __syncthreads();
    }
    const int p = blockIdx.y * 256 + tid, y = p >> 6, xx = p & 63;
    const bool vt = y > 0, vb = y < HH - 1, vl = xx > 0, vr = xx < WW - 1;
    const bool val[9] = { vt && vl, vt, vt && vr, vl, true, vr, vb && vl, vb, vb && vr };
    const int off9[9] = { -WW - 1, -WW, -WW + 1, -1, 0, 1, WW - 1, WW, WW + 1 };
    const float* xbp = x + (size_t)b * CIN * NPIX + p;
    float acc = 0.f;
    for (int ci = 0; ci < CIN; ++ci) {
        const float* xp = xbp + ci * NPIX;
        const float* wp = wsh + ci * 9;
#pragma unroll
        for (int r = 0; r < 9; ++r) acc += (val[r] ? xp[off9[r]] : 0.f) * wp[r];
    }
    out[(size_t)bc * NPIX + p] = acc;
}

// ---------------------------------------------------------------------------
extern "C" void kernel_launch(void* const* d_in, const int* in_sizes, int n_in,
                              void* d_out, int out_size, void* d_ws, size_t ws_size,
                              hipStream_t stream) {
    const float* x       = (const float*)d_in[0];
    const float* w_style = (const float*)d_in[1];
    const float* W       = (const float*)d_in[2];
    const float* aff_w   = (const float*)d_in[3];
    const float* aff_b   = (const float*)d_in[4];
    float* out = (float*)d_out;

    const size_t wt_off  = 65536;
    const size_t wt_sz   = (size_t)BATCH * 9 * COUT * CIN * sizeof(bf16);
    const size_t xt_off  = wt_off + wt_sz;
    const size_t xt_sz   = (size_t)BATCH * PADH * PADW * CIN * sizeof(bf16);
    const size_t need    = xt_off + xt_sz;

    if (ws_size >= need) {
        float* s  = (float*)d_ws;
        bf16* wt  = (bf16*)((char*)d_ws + wt_off);
        bf16* xt  = (bf16*)((char*)d_ws + xt_off);
        style_kernel<<<dim3(BATCH), dim3(256), 0, stream>>>(w_style, aff_w, aff_b, s);
        prep_kernel<<<dim3(BATCH * COUT + BATCH * PADH), dim3(256), 0, stream>>>(
            W, s, x, wt, xt);
        gemm_kernel<<<dim3(BATCH * 16), dim3(512), 0, stream>>>(xt, wt, out);
    } else if (ws_size >= (size_t)(BATCH * CIN * sizeof(float))) {
        float* s = (float*)d_ws;
        style_kernel<<<dim3(BATCH), dim3(256), 0, stream>>>(w_style, aff_w, aff_b, s);
        conv_mod_kernel<false><<<dim3(BATCH * COUT, NPIX / 256), dim3(256), 0, stream>>>(
            x, W, s, w_style, aff_w, aff_b, out);
    } else {
        conv_mod_kernel<true><<<dim3(BATCH * COUT, NPIX / 256), dim3(256), 0, stream>>>(
            x, W, nullptr, w_style, aff_w, aff_b, out);
    }
}